// Round 9
// baseline (108.565 us; speedup 1.0000x reference)
//
#include <hip/hip_runtime.h>

// Problem constants: B=8, N=1024, F=128, H=4, K=32, TAU=1
typedef unsigned int uint32;
typedef unsigned short ushort16;

#define P1_PTS 16      // points per A-block
#define P1_BLOCKS 512  // 8192 / P1_PTS  == 256 CU x 2 blocks/CU (co-resident)
#define NCHUNK_B 64    // chunks per batch = 1024 / P1_PTS

// round-to-nearest-even f32 -> bf16 bits
static __device__ __forceinline__ ushort16 f2bf(float f) {
  uint32 u = __float_as_uint(f);
  return (ushort16)((u + 0x7FFFu + ((u >> 16) & 1u)) >> 16);
}

// ---------------------------------------------------------------------------
// Prep: transpose keys into KTQ[fq][hk] (float4 = K[hk][4fq..4fq+3]) and
// zero the grid-barrier counter (re-zeroed every call -> deterministic).
// ---------------------------------------------------------------------------
__global__ __launch_bounds__(256) void mempool_prep(
    const float* __restrict__ keys, float* __restrict__ ktq,
    unsigned* __restrict__ bar) {
  if (blockIdx.x == 0 && threadIdx.x == 0) *bar = 0u;
  const int i = blockIdx.x * 256 + threadIdx.x;  // 0..4095
  const int fq = i >> 7;
  const int hk = i & 127;
  reinterpret_cast<float4*>(ktq)[i] =
      reinterpret_cast<const float4*>(keys)[hk * 32 + fq];
}

// ---------------------------------------------------------------------------
// Fused kernel: A-phase (distances -> Student-t -> per-head normalize ->
// conv-combine -> softmax -> S_out + bf16 partial pooled -> part), then an
// in-kernel device-wide barrier (all 512 blocks co-resident by construction:
// launch_bounds(256,2) => VGPR<=128, LDS 50KB<=80KB => 2 blocks/CU x 256 CU),
// then blocks 0..255 run the out-phase (chunk-reduce + matvec + LeakyReLU).
// ---------------------------------------------------------------------------
__global__ __launch_bounds__(256, 2) void mempool_fused(
    const float* __restrict__ x, const float* __restrict__ ktq,
    const float* __restrict__ conv_w, const float* __restrict__ lin_w,
    float* __restrict__ S_out, ushort16* __restrict__ part,
    unsigned* __restrict__ bar, float* __restrict__ out) {
  const int t = threadIdx.x;
  const int hkp = t & 63;
  const int q = t >> 6;  // f-quarter 0..3

  __shared__ float4 xl[P1_PTS * 32];      // [p][fq], 8 KB
  __shared__ float accs[P1_PTS][4][128];  // [p][q][hk], 32 KB
  __shared__ float cwsn[P1_PTS][4][32];   // [p][h][k], 8 KB
  __shared__ float sl[P1_PTS][32];        // [p][k], 2 KB

  const int bn0 = blockIdx.x * P1_PTS;

  // ---- A-phase ------------------------------------------------------------
  {
    const float4* xg = reinterpret_cast<const float4*>(x) + (size_t)bn0 * 32;
    xl[t] = xg[t];
    xl[t + 256] = xg[t + 256];
  }
  __syncthreads();

  const float4* kq =
      reinterpret_cast<const float4*>(ktq) + (size_t)(q * 8) * 128 + hkp;

  float acc0[P1_PTS], acc1[P1_PTS];
#pragma unroll
  for (int p = 0; p < P1_PTS; ++p) acc0[p] = acc1[p] = 0.f;

#pragma unroll
  for (int j = 0; j < 8; ++j) {
    const float4 kv0 = kq[j * 128];       // coalesced (lanes 0..63 contiguous)
    const float4 kv1 = kq[j * 128 + 64];  // second key row
    const int jj = q * 8 + j;
#pragma unroll
    for (int p = 0; p < P1_PTS; ++p) {
      const float4 xv = xl[p * 32 + jj];  // uniform ds_read -> broadcast
      acc0[p] += fabsf(kv0.x - xv.x) + fabsf(kv0.y - xv.y) +
                 fabsf(kv0.z - xv.z) + fabsf(kv0.w - xv.w);
      acc1[p] += fabsf(kv1.x - xv.x) + fabsf(kv1.y - xv.y) +
                 fabsf(kv1.z - xv.z) + fabsf(kv1.w - xv.w);
    }
  }

#pragma unroll
  for (int p = 0; p < P1_PTS; ++p) {
    accs[p][q][hkp] = acc0[p];
    accs[p][q][hkp + 64] = acc1[p];
  }
  __syncthreads();

  // Quarter-combine + Student-t + per-head normalize.
  const float4 cwv = *reinterpret_cast<const float4*>(conv_w);
  {
    const int hk = t & 127;
    const float cw = (hk & 64) ? ((hk & 32) ? cwv.w : cwv.z)
                               : ((hk & 32) ? cwv.y : cwv.x);
#pragma unroll
    for (int i = 0; i < 8; ++i) {
      const int p = (t >> 7) + 2 * i;
      const float d = accs[p][0][hk] + accs[p][1][hk] + accs[p][2][hk] +
                      accs[p][3][hk];
      const float tv = __builtin_amdgcn_rcpf(1.f + d * d);  // Student-t, tau=1
      float hs = tv;
#pragma unroll
      for (int m = 1; m < 32; m <<= 1) hs += __shfl_xor(hs, m);
      cwsn[p][hk >> 5][hk & 31] = cw * tv * __builtin_amdgcn_rcpf(hs);
    }
  }
  __syncthreads();

  // Conv-combine over heads + softmax over k. 16 p x 32 k = 2 passes.
#pragma unroll
  for (int pp = 0; pp < 2; ++pp) {
    const int p = pp * 8 + (t >> 5);
    const int k = t & 31;
    float sc = cwsn[p][0][k] + cwsn[p][1][k] + cwsn[p][2][k] + cwsn[p][3][k];
    float mx = sc;
#pragma unroll
    for (int m = 1; m < 32; m <<= 1) mx = fmaxf(mx, __shfl_xor(mx, m));
    const float e = __expf(sc - mx);
    float se = e;
#pragma unroll
    for (int m = 1; m < 32; m <<= 1) se += __shfl_xor(se, m);
    const float sv = e * __builtin_amdgcn_rcpf(se);
    S_out[(size_t)(bn0 + p) * 32 + k] = sv;
    sl[p][k] = sv;
  }
  __syncthreads();

  // Partial pooled (bf16): thread = (k = t&31, fs = t>>5).
  {
    const int k = t & 31;
    const int fs = t >> 5;
    float4 a0 = {0, 0, 0, 0}, a1 = {0, 0, 0, 0}, a2 = {0, 0, 0, 0},
           a3 = {0, 0, 0, 0};
#pragma unroll
    for (int p = 0; p < P1_PTS; ++p) {
      const float s = sl[p][k];
      const float4 v0 = xl[p * 32 + fs * 4 + 0];
      const float4 v1 = xl[p * 32 + fs * 4 + 1];
      const float4 v2 = xl[p * 32 + fs * 4 + 2];
      const float4 v3 = xl[p * 32 + fs * 4 + 3];
      a0.x += s * v0.x; a0.y += s * v0.y; a0.z += s * v0.z; a0.w += s * v0.w;
      a1.x += s * v1.x; a1.y += s * v1.y; a1.z += s * v1.z; a1.w += s * v1.w;
      a2.x += s * v2.x; a2.y += s * v2.y; a2.z += s * v2.z; a2.w += s * v2.w;
      a3.x += s * v3.x; a3.y += s * v3.y; a3.z += s * v3.z; a3.w += s * v3.w;
    }
    uint32 w0 = f2bf(a0.x) | ((uint32)f2bf(a0.y) << 16);
    uint32 w1 = f2bf(a0.z) | ((uint32)f2bf(a0.w) << 16);
    uint32 w2 = f2bf(a1.x) | ((uint32)f2bf(a1.y) << 16);
    uint32 w3 = f2bf(a1.z) | ((uint32)f2bf(a1.w) << 16);
    uint32 w4 = f2bf(a2.x) | ((uint32)f2bf(a2.y) << 16);
    uint32 w5 = f2bf(a2.z) | ((uint32)f2bf(a2.w) << 16);
    uint32 w6 = f2bf(a3.x) | ((uint32)f2bf(a3.y) << 16);
    uint32 w7 = f2bf(a3.z) | ((uint32)f2bf(a3.w) << 16);
    uint4* dst = reinterpret_cast<uint4*>(
        part + (((size_t)blockIdx.x * 32 + k) * 128 + fs * 16));
    dst[0] = make_uint4(w0, w1, w2, w3);
    dst[1] = make_uint4(w4, w5, w6, w7);
  }

  // ---- device-wide barrier ------------------------------------------------
  // Release: each thread drains its stores to L2, then thread 0's ACQ_REL
  // atomic performs the agent-scope L2 writeback (cross-XCD visibility).
  __threadfence();
  __syncthreads();
  if (t == 0) {
    __hip_atomic_fetch_add(bar, 1u, __ATOMIC_ACQ_REL,
                           __HIP_MEMORY_SCOPE_AGENT);
  }
  if (blockIdx.x >= 256) return;  // non-out blocks free their CU slot

  if (t == 0) {
    unsigned v;
    do {
      __builtin_amdgcn_s_sleep(2);
      v = __hip_atomic_load(bar, __ATOMIC_RELAXED, __HIP_MEMORY_SCOPE_AGENT);
    } while (v < (unsigned)P1_BLOCKS);
    __threadfence();  // acquire: invalidate L2 so part reads are fresh
  }
  __syncthreads();

  // ---- out-phase (blocks 0..255 = (b = bid>>5, k = bid&31)) --------------
  {
    const int b = blockIdx.x >> 5;
    const int k = blockIdx.x & 31;
    const int f2 = t & 63;
    const int ch = t >> 6;  // 0..3

    float* red = &accs[0][0][0];    // alias: [4][128]
    float* pooled = &cwsn[0][0][0]; // alias: [128]

    float sx = 0.f, sy = 0.f;
    const uint32* pp = reinterpret_cast<const uint32*>(part) +
                       ((size_t)((b * NCHUNK_B + ch * 16) * 32 + k)) * 64 + f2;
#pragma unroll
    for (int cc = 0; cc < 16; ++cc) {
      const uint32 v = pp[(size_t)cc * 32 * 64];
      sx += __uint_as_float(v << 16);
      sy += __uint_as_float(v & 0xFFFF0000u);
    }
    red[ch * 128 + f2 * 2] = sx;
    red[ch * 128 + f2 * 2 + 1] = sy;
    __syncthreads();

    if (t < 128)
      pooled[t] = red[0 * 128 + t] + red[1 * 128 + t] + red[2 * 128 + t] +
                  red[3 * 128 + t];
    __syncthreads();

    if (t < 128) {
      const float4* w4 = reinterpret_cast<const float4*>(lin_w) + t * 32;
      const float4* pl4 = reinterpret_cast<const float4*>(pooled);
      float o = 0.f;
#pragma unroll
      for (int j = 0; j < 32; ++j) {
        const float4 w = w4[j];
        const float4 p = pl4[j];
        o += w.x * p.x + w.y * p.y + w.z * p.z + w.w * p.w;
      }
      o = (o >= 0.f) ? o : 0.01f * o;
      out[(size_t)(b * 32 + k) * 128 + t] = o;
    }
  }
}

// ---------------------------------------------------------------------------
// Fallbacks (no workspace): round-1 structure (known-good).
// ---------------------------------------------------------------------------
__global__ __launch_bounds__(256) void mempool_phase1_fb(
    const float* __restrict__ x, const float* __restrict__ keys,
    const float* __restrict__ conv_w, float* __restrict__ S_out) {
  const int t = threadIdx.x;
  const int hk = t & 127;
  const int half = t >> 7;

  const float4* kq = reinterpret_cast<const float4*>(keys) + hk * 32 + half * 16;
  const float cw = conv_w[(t >> 5) & 3];

  __shared__ float lds_half[128];
  __shared__ float lds_ws[128];

  const int base = blockIdx.x * 8;
  for (int p = 0; p < 8; ++p) {
    const int bn = base + p;
    const float4* xq = reinterpret_cast<const float4*>(x) + bn * 32 + half * 16;
    float a0 = 0.f;
#pragma unroll
    for (int j = 0; j < 16; ++j) {
      const float4 kv = kq[j];
      const float4 xv = xq[j];
      a0 += fabsf(kv.x - xv.x) + fabsf(kv.y - xv.y) + fabsf(kv.z - xv.z) +
            fabsf(kv.w - xv.w);
    }
    if (t >= 128) lds_half[hk] = a0;
    __syncthreads();
    if (t < 128) {
      const float d = a0 + lds_half[hk];
      const float tv = 1.0f / (1.0f + d * d);
      float hs = tv;
#pragma unroll
      for (int m = 1; m < 32; m <<= 1) hs += __shfl_xor(hs, m);
      lds_ws[hk] = cw * tv / hs;
    }
    __syncthreads();
    if (t < 32) {
      float sc = lds_ws[t] + lds_ws[32 + t] + lds_ws[64 + t] + lds_ws[96 + t];
      float mx = sc;
#pragma unroll
      for (int m = 1; m < 32; m <<= 1) mx = fmaxf(mx, __shfl_xor(mx, m));
      const float e = __expf(sc - mx);
      float se = e;
#pragma unroll
      for (int m = 1; m < 32; m <<= 1) se += __shfl_xor(se, m);
      S_out[bn * 32 + t] = e / se;
    }
    __syncthreads();
  }
}

__global__ __launch_bounds__(256) void mempool_phase2_fb(
    const float* __restrict__ x, const float* __restrict__ S,
    const float* __restrict__ lin_w, float* __restrict__ out) {
  const int b = blockIdx.x >> 5;
  const int k = blockIdx.x & 31;
  const int t = threadIdx.x;
  const int fq = t & 31;
  const int seg = t >> 5;

  const float4* xq = reinterpret_cast<const float4*>(x) + (size_t)b * 1024 * 32;
  const float* Sb = S + (size_t)b * 1024 * 32 + k;

  float4 acc = {0.f, 0.f, 0.f, 0.f};
  const int n0 = seg * 128;
#pragma unroll 4
  for (int n = n0; n < n0 + 128; ++n) {
    const float sv = Sb[(size_t)n * 32];
    const float4 xv = xq[n * 32 + fq];
    acc.x += sv * xv.x;
    acc.y += sv * xv.y;
    acc.z += sv * xv.z;
    acc.w += sv * xv.w;
  }

  __shared__ float4 red[8][32];
  red[seg][fq] = acc;
  __syncthreads();

  __shared__ float4 pooled4[32];
  if (t < 32) {
    float4 a = red[0][t];
#pragma unroll
    for (int ss = 1; ss < 8; ++ss) {
      const float4 r = red[ss][t];
      a.x += r.x; a.y += r.y; a.z += r.z; a.w += r.w;
    }
    pooled4[t] = a;
  }
  __syncthreads();

  if (t < 128) {
    const float4* wq = reinterpret_cast<const float4*>(lin_w) + t * 32;
    float o = 0.f;
#pragma unroll
    for (int j = 0; j < 32; ++j) {
      const float4 w = wq[j];
      const float4 p = pooled4[j];
      o += w.x * p.x + w.y * p.y + w.z * p.z + w.w * p.w;
    }
    o = (o >= 0.f) ? o : 0.01f * o;
    out[(size_t)(b * 32 + k) * 128 + t] = o;
  }
}

extern "C" void kernel_launch(void* const* d_in, const int* in_sizes, int n_in,
                              void* d_out, int out_size, void* d_ws, size_t ws_size,
                              hipStream_t stream) {
  const float* x = (const float*)d_in[0];       // [8,1024,128]
  const float* keys = (const float*)d_in[1];    // [4,32,128]
  const float* conv_w = (const float*)d_in[2];  // [4]
  const float* lin_w = (const float*)d_in[3];   // [128,128]

  float* out = (float*)d_out;            // [8,32,128]
  float* S_out = (float*)d_out + 32768;  // [8,1024,32]

  const size_t ktq_bytes = 128 * 128 * sizeof(float);          // 64 KB
  const size_t part_bytes = (size_t)P1_BLOCKS * 32 * 128 * 2;  // 4 MB
  const size_t bar_bytes = 64;
  const size_t need = ktq_bytes + part_bytes + bar_bytes;

  if (ws_size >= need) {
    float* ktq = (float*)d_ws;
    ushort16* part = (ushort16*)((char*)d_ws + ktq_bytes);
    unsigned* bar = (unsigned*)((char*)d_ws + ktq_bytes + part_bytes);
    mempool_prep<<<16, 256, 0, stream>>>(keys, ktq, bar);
    mempool_fused<<<P1_BLOCKS, 256, 0, stream>>>(x, ktq, conv_w, lin_w, S_out,
                                                 part, bar, out);
  } else {
    mempool_phase1_fb<<<1024, 256, 0, stream>>>(x, keys, conv_w, S_out);
    mempool_phase2_fb<<<8 * 32, 256, 0, stream>>>(x, S_out, lin_w, out);
  }
}

// Round 10
// 52.959 us; speedup vs baseline: 2.0500x; 2.0500x over previous
//
#include <hip/hip_runtime.h>

// Problem constants: B=8, N=1024, F=128, H=4, K=32, TAU=1
typedef unsigned int uint32;
typedef unsigned short ushort16;

#define P1_PTS 16      // points per A-block
#define P1_BLOCKS 512  // 8192 / P1_PTS; 50KB LDS -> 3 blk/CU cap >= 2 avg -> all co-resident
#define NCHUNK_B 64    // chunks per batch = 1024 / P1_PTS

// round-to-nearest-even f32 -> bf16 bits
static __device__ __forceinline__ ushort16 f2bf(float f) {
  uint32 u = __float_as_uint(f);
  return (ushort16)((u + 0x7FFFu + ((u >> 16) & 1u)) >> 16);
}

// ---------------------------------------------------------------------------
// Prep: transpose keys into KTQ[fq][hk] (float4 = K[hk][4fq..4fq+3]) and
// zero the grid-barrier counter (re-zeroed every call -> deterministic).
// ---------------------------------------------------------------------------
__global__ __launch_bounds__(256) void mempool_prep(
    const float* __restrict__ keys, float* __restrict__ ktq,
    unsigned* __restrict__ bar) {
  if (blockIdx.x == 0 && threadIdx.x == 0)
    __hip_atomic_store(bar, 0u, __ATOMIC_RELAXED, __HIP_MEMORY_SCOPE_AGENT);
  const int i = blockIdx.x * 256 + threadIdx.x;  // 0..4095
  const int fq = i >> 7;
  const int hk = i & 127;
  reinterpret_cast<float4*>(ktq)[i] =
      reinterpret_cast<const float4*>(keys)[hk * 32 + fq];
}

// ---------------------------------------------------------------------------
// Fused kernel. A-phase (distances -> Student-t -> normalize -> conv ->
// softmax -> S_out; bf16 partial pooled -> part via AGENT-scope sc1 stores,
// which land at the coherent point: NO L2-writeback fence needed). Then a
// fence-free device barrier (vmcnt-drained by __syncthreads + relaxed agent
// atomics), then blocks 0..255 buffer_inv once (ACQUIRE) and run out-phase.
// All 512 blocks co-resident: 50 KB LDS -> 3 blk/CU cap, 512 <= 768.
// ---------------------------------------------------------------------------
__global__ __launch_bounds__(256, 2) void mempool_fused(
    const float* __restrict__ x, const float* __restrict__ ktq,
    const float* __restrict__ conv_w, const float* __restrict__ lin_w,
    float* __restrict__ S_out, uint32* __restrict__ part,
    unsigned* __restrict__ bar, float* __restrict__ out) {
  const int t = threadIdx.x;
  const int hkp = t & 63;
  const int q = t >> 6;  // f-quarter 0..3

  __shared__ float4 xl[P1_PTS * 32];      // [p][fq], 8 KB
  __shared__ float accs[P1_PTS][4][128];  // [p][q][hk], 32 KB
  __shared__ float cwsn[P1_PTS][4][32];   // [p][h][k], 8 KB
  __shared__ float sl[P1_PTS][32];        // [p][k], 2 KB

  const int bn0 = blockIdx.x * P1_PTS;

  // ---- A-phase ------------------------------------------------------------
  {
    const float4* xg = reinterpret_cast<const float4*>(x) + (size_t)bn0 * 32;
    xl[t] = xg[t];
    xl[t + 256] = xg[t + 256];
  }
  __syncthreads();

  const float4* kq =
      reinterpret_cast<const float4*>(ktq) + (size_t)(q * 8) * 128 + hkp;

  float acc0[P1_PTS], acc1[P1_PTS];
#pragma unroll
  for (int p = 0; p < P1_PTS; ++p) acc0[p] = acc1[p] = 0.f;

#pragma unroll
  for (int j = 0; j < 8; ++j) {
    const float4 kv0 = kq[j * 128];       // coalesced (lanes 0..63 contiguous)
    const float4 kv1 = kq[j * 128 + 64];  // second key row
    const int jj = q * 8 + j;
#pragma unroll
    for (int p = 0; p < P1_PTS; ++p) {
      const float4 xv = xl[p * 32 + jj];  // uniform ds_read -> broadcast
      acc0[p] += fabsf(kv0.x - xv.x) + fabsf(kv0.y - xv.y) +
                 fabsf(kv0.z - xv.z) + fabsf(kv0.w - xv.w);
      acc1[p] += fabsf(kv1.x - xv.x) + fabsf(kv1.y - xv.y) +
                 fabsf(kv1.z - xv.z) + fabsf(kv1.w - xv.w);
    }
  }

#pragma unroll
  for (int p = 0; p < P1_PTS; ++p) {
    accs[p][q][hkp] = acc0[p];
    accs[p][q][hkp + 64] = acc1[p];
  }
  __syncthreads();

  // Quarter-combine + Student-t + per-head normalize.
  const float4 cwv = *reinterpret_cast<const float4*>(conv_w);
  {
    const int hk = t & 127;
    const float cw = (hk & 64) ? ((hk & 32) ? cwv.w : cwv.z)
                               : ((hk & 32) ? cwv.y : cwv.x);
#pragma unroll
    for (int i = 0; i < 8; ++i) {
      const int p = (t >> 7) + 2 * i;
      const float d = accs[p][0][hk] + accs[p][1][hk] + accs[p][2][hk] +
                      accs[p][3][hk];
      const float tv = __builtin_amdgcn_rcpf(1.f + d * d);  // Student-t, tau=1
      float hs = tv;
#pragma unroll
      for (int m = 1; m < 32; m <<= 1) hs += __shfl_xor(hs, m);
      cwsn[p][hk >> 5][hk & 31] = cw * tv * __builtin_amdgcn_rcpf(hs);
    }
  }
  __syncthreads();

  // Conv-combine over heads + softmax over k. 16 p x 32 k = 2 passes.
#pragma unroll
  for (int pp = 0; pp < 2; ++pp) {
    const int p = pp * 8 + (t >> 5);
    const int k = t & 31;
    float sc = cwsn[p][0][k] + cwsn[p][1][k] + cwsn[p][2][k] + cwsn[p][3][k];
    float mx = sc;
#pragma unroll
    for (int m = 1; m < 32; m <<= 1) mx = fmaxf(mx, __shfl_xor(mx, m));
    const float e = __expf(sc - mx);
    float se = e;
#pragma unroll
    for (int m = 1; m < 32; m <<= 1) se += __shfl_xor(se, m);
    const float sv = e * __builtin_amdgcn_rcpf(se);
    S_out[(size_t)(bn0 + p) * 32 + k] = sv;
    sl[p][k] = sv;
  }
  __syncthreads();

  // Partial pooled (bf16 pairs packed in uint32), AGENT-scope stores
  // (sc1 -> coherent point; no dirty L2, so no wbl2 fence needed).
  {
    const int k = t & 31;
    const int fs = t >> 5;
    float4 a0 = {0, 0, 0, 0}, a1 = {0, 0, 0, 0}, a2 = {0, 0, 0, 0},
           a3 = {0, 0, 0, 0};
#pragma unroll
    for (int p = 0; p < P1_PTS; ++p) {
      const float s = sl[p][k];
      const float4 v0 = xl[p * 32 + fs * 4 + 0];
      const float4 v1 = xl[p * 32 + fs * 4 + 1];
      const float4 v2 = xl[p * 32 + fs * 4 + 2];
      const float4 v3 = xl[p * 32 + fs * 4 + 3];
      a0.x += s * v0.x; a0.y += s * v0.y; a0.z += s * v0.z; a0.w += s * v0.w;
      a1.x += s * v1.x; a1.y += s * v1.y; a1.z += s * v1.z; a1.w += s * v1.w;
      a2.x += s * v2.x; a2.y += s * v2.y; a2.z += s * v2.z; a2.w += s * v2.w;
      a3.x += s * v3.x; a3.y += s * v3.y; a3.z += s * v3.z; a3.w += s * v3.w;
    }
    uint32* dst = part + (((size_t)blockIdx.x * 32 + k) * 64 + fs * 8);
    const uint32 w[8] = {
        f2bf(a0.x) | ((uint32)f2bf(a0.y) << 16),
        f2bf(a0.z) | ((uint32)f2bf(a0.w) << 16),
        f2bf(a1.x) | ((uint32)f2bf(a1.y) << 16),
        f2bf(a1.z) | ((uint32)f2bf(a1.w) << 16),
        f2bf(a2.x) | ((uint32)f2bf(a2.y) << 16),
        f2bf(a2.z) | ((uint32)f2bf(a2.w) << 16),
        f2bf(a3.x) | ((uint32)f2bf(a3.y) << 16),
        f2bf(a3.z) | ((uint32)f2bf(a3.w) << 16)};
#pragma unroll
    for (int i = 0; i < 8; ++i)
      __hip_atomic_store(dst + i, w[i], __ATOMIC_RELAXED,
                         __HIP_MEMORY_SCOPE_AGENT);
  }

  // ---- fence-free device barrier -----------------------------------------
  // __syncthreads drains vmcnt (sc1 stores ack'd at the coherent point),
  // then one relaxed agent RMW per block counts completion.
  __syncthreads();
  if (t == 0)
    __hip_atomic_fetch_add(bar, 1u, __ATOMIC_RELAXED,
                           __HIP_MEMORY_SCOPE_AGENT);
  if (blockIdx.x >= 256) return;  // non-out blocks free their CU slot

  if (t == 0) {
    while (__hip_atomic_load(bar, __ATOMIC_RELAXED,
                             __HIP_MEMORY_SCOPE_AGENT) < (unsigned)P1_BLOCKS)
      __builtin_amdgcn_s_sleep(2);
    // single ACQUIRE (buffer_inv): drop stale L2 lines so the normal
    // vectorized part reads below refetch from the coherent point.
    (void)__hip_atomic_load(bar, __ATOMIC_ACQUIRE, __HIP_MEMORY_SCOPE_AGENT);
  }
  __syncthreads();

  // ---- out-phase (blocks 0..255 = (b = bid>>5, k = bid&31)) --------------
  {
    const int b = blockIdx.x >> 5;
    const int k = blockIdx.x & 31;
    const int f2 = t & 63;
    const int ch = t >> 6;  // 0..3

    float* red = &accs[0][0][0];     // alias: [4][128]
    float* pooled = &cwsn[0][0][0];  // alias: [128]

    float sx = 0.f, sy = 0.f;
    const uint32* pp =
        part + ((size_t)((b * NCHUNK_B + ch * 16) * 32 + k)) * 64 + f2;
#pragma unroll
    for (int cc = 0; cc < 16; ++cc) {
      const uint32 v = pp[(size_t)cc * 32 * 64];
      sx += __uint_as_float(v << 16);
      sy += __uint_as_float(v & 0xFFFF0000u);
    }
    red[ch * 128 + f2 * 2] = sx;
    red[ch * 128 + f2 * 2 + 1] = sy;
    __syncthreads();

    if (t < 128)
      pooled[t] = red[0 * 128 + t] + red[1 * 128 + t] + red[2 * 128 + t] +
                  red[3 * 128 + t];
    __syncthreads();

    if (t < 128) {
      const float4* w4 = reinterpret_cast<const float4*>(lin_w) + t * 32;
      const float4* pl4 = reinterpret_cast<const float4*>(pooled);
      float o = 0.f;
#pragma unroll
      for (int j = 0; j < 32; ++j) {
        const float4 w = w4[j];
        const float4 p = pl4[j];
        o += w.x * p.x + w.y * p.y + w.z * p.z + w.w * p.w;
      }
      o = (o >= 0.f) ? o : 0.01f * o;
      out[(size_t)(b * 32 + k) * 128 + t] = o;
    }
  }
}

// ---------------------------------------------------------------------------
// Fallbacks (no workspace): round-1 structure (known-good).
// ---------------------------------------------------------------------------
__global__ __launch_bounds__(256) void mempool_phase1_fb(
    const float* __restrict__ x, const float* __restrict__ keys,
    const float* __restrict__ conv_w, float* __restrict__ S_out) {
  const int t = threadIdx.x;
  const int hk = t & 127;
  const int half = t >> 7;

  const float4* kq = reinterpret_cast<const float4*>(keys) + hk * 32 + half * 16;
  const float cw = conv_w[(t >> 5) & 3];

  __shared__ float lds_half[128];
  __shared__ float lds_ws[128];

  const int base = blockIdx.x * 8;
  for (int p = 0; p < 8; ++p) {
    const int bn = base + p;
    const float4* xq = reinterpret_cast<const float4*>(x) + bn * 32 + half * 16;
    float a0 = 0.f;
#pragma unroll
    for (int j = 0; j < 16; ++j) {
      const float4 kv = kq[j];
      const float4 xv = xq[j];
      a0 += fabsf(kv.x - xv.x) + fabsf(kv.y - xv.y) + fabsf(kv.z - xv.z) +
            fabsf(kv.w - xv.w);
    }
    if (t >= 128) lds_half[hk] = a0;
    __syncthreads();
    if (t < 128) {
      const float d = a0 + lds_half[hk];
      const float tv = 1.0f / (1.0f + d * d);
      float hs = tv;
#pragma unroll
      for (int m = 1; m < 32; m <<= 1) hs += __shfl_xor(hs, m);
      lds_ws[hk] = cw * tv / hs;
    }
    __syncthreads();
    if (t < 32) {
      float sc = lds_ws[t] + lds_ws[32 + t] + lds_ws[64 + t] + lds_ws[96 + t];
      float mx = sc;
#pragma unroll
      for (int m = 1; m < 32; m <<= 1) mx = fmaxf(mx, __shfl_xor(mx, m));
      const float e = __expf(sc - mx);
      float se = e;
#pragma unroll
      for (int m = 1; m < 32; m <<= 1) se += __shfl_xor(se, m);
      S_out[bn * 32 + t] = e / se;
    }
    __syncthreads();
  }
}

__global__ __launch_bounds__(256) void mempool_phase2_fb(
    const float* __restrict__ x, const float* __restrict__ S,
    const float* __restrict__ lin_w, float* __restrict__ out) {
  const int b = blockIdx.x >> 5;
  const int k = blockIdx.x & 31;
  const int t = threadIdx.x;
  const int fq = t & 31;
  const int seg = t >> 5;

  const float4* xq = reinterpret_cast<const float4*>(x) + (size_t)b * 1024 * 32;
  const float* Sb = S + (size_t)b * 1024 * 32 + k;

  float4 acc = {0.f, 0.f, 0.f, 0.f};
  const int n0 = seg * 128;
#pragma unroll 4
  for (int n = n0; n < n0 + 128; ++n) {
    const float sv = Sb[(size_t)n * 32];
    const float4 xv = xq[n * 32 + fq];
    acc.x += sv * xv.x;
    acc.y += sv * xv.y;
    acc.z += sv * xv.z;
    acc.w += sv * xv.w;
  }

  __shared__ float4 red[8][32];
  red[seg][fq] = acc;
  __syncthreads();

  __shared__ float4 pooled4[32];
  if (t < 32) {
    float4 a = red[0][t];
#pragma unroll
    for (int ss = 1; ss < 8; ++ss) {
      const float4 r = red[ss][t];
      a.x += r.x; a.y += r.y; a.z += r.z; a.w += r.w;
    }
    pooled4[t] = a;
  }
  __syncthreads();

  if (t < 128) {
    const float4* wq = reinterpret_cast<const float4*>(lin_w) + t * 32;
    float o = 0.f;
#pragma unroll
    for (int j = 0; j < 32; ++j) {
      const float4 w = wq[j];
      const float4 p = pooled4[j];
      o += w.x * p.x + w.y * p.y + w.z * p.z + w.w * p.w;
    }
    o = (o >= 0.f) ? o : 0.01f * o;
    out[(size_t)(b * 32 + k) * 128 + t] = o;
  }
}

extern "C" void kernel_launch(void* const* d_in, const int* in_sizes, int n_in,
                              void* d_out, int out_size, void* d_ws, size_t ws_size,
                              hipStream_t stream) {
  const float* x = (const float*)d_in[0];       // [8,1024,128]
  const float* keys = (const float*)d_in[1];    // [4,32,128]
  const float* conv_w = (const float*)d_in[2];  // [4]
  const float* lin_w = (const float*)d_in[3];   // [128,128]

  float* out = (float*)d_out;            // [8,32,128]
  float* S_out = (float*)d_out + 32768;  // [8,1024,32]

  const size_t ktq_bytes = 128 * 128 * sizeof(float);          // 64 KB
  const size_t part_bytes = (size_t)P1_BLOCKS * 32 * 128 * 2;  // 4 MB
  const size_t bar_bytes = 64;
  const size_t need = ktq_bytes + part_bytes + bar_bytes;

  if (ws_size >= need) {
    float* ktq = (float*)d_ws;
    uint32* part = (uint32*)((char*)d_ws + ktq_bytes);
    unsigned* bar = (unsigned*)((char*)d_ws + ktq_bytes + part_bytes);
    mempool_prep<<<16, 256, 0, stream>>>(keys, ktq, bar);
    mempool_fused<<<P1_BLOCKS, 256, 0, stream>>>(x, ktq, conv_w, lin_w, S_out,
                                                 part, bar, out);
  } else {
    mempool_phase1_fb<<<1024, 256, 0, stream>>>(x, keys, conv_w, S_out);
    mempool_phase2_fb<<<8 * 32, 256, 0, stream>>>(x, S_out, lin_w, out);
  }
}

// Round 12
// 47.485 us; speedup vs baseline: 2.2863x; 1.1153x over previous
//
#include <hip/hip_runtime.h>

// Problem constants: B=8, N=1024, F=128, H=4, K=32, TAU=1
typedef unsigned int uint32;
typedef unsigned short ushort16;
typedef unsigned int uint32x4 __attribute__((ext_vector_type(4)));

#define P1_PTS 16      // points per A-block
#define P1_BLOCKS 512  // 8192 / P1_PTS; 50KB LDS + 256thr -> 2 blk/CU, all co-resident
#define NCHUNK_B 64    // chunks per batch = 1024 / P1_PTS

// round-to-nearest-even f32 -> bf16 bits
static __device__ __forceinline__ ushort16 f2bf(float f) {
  uint32 u = __float_as_uint(f);
  return (ushort16)((u + 0x7FFFu + ((u >> 16) & 1u)) >> 16);
}

// ---------------------------------------------------------------------------
// Prep: transpose keys into KTQ[fq][hk] (float4 = K[hk][4fq..4fq+3]) and
// zero the grid-barrier counter (re-zeroed every call -> deterministic).
// ---------------------------------------------------------------------------
__global__ __launch_bounds__(256) void mempool_prep(
    const float* __restrict__ keys, float* __restrict__ ktq,
    unsigned* __restrict__ bar) {
  if (blockIdx.x == 0 && threadIdx.x == 0)
    __hip_atomic_store(bar, 0u, __ATOMIC_RELAXED, __HIP_MEMORY_SCOPE_AGENT);
  const int i = blockIdx.x * 256 + threadIdx.x;  // 0..4095
  const int fq = i >> 7;
  const int hk = i & 127;
  reinterpret_cast<float4*>(ktq)[i] =
      reinterpret_cast<const float4*>(keys)[hk * 32 + fq];
}

// ---------------------------------------------------------------------------
// Fused kernel. A-phase (distances -> Student-t -> normalize -> conv ->
// softmax -> S_out; bf16 partial pooled -> part). part is written with
// COALESCED write-through stores (global_store_dwordx4 sc0 sc1 -> coherent
// point, 16B/lane; r10's 8 scalar sc1 stores caused 34 MB of HBM sector
// writes = the 51 us). Fence-free device barrier: s_waitcnt vmcnt(0)
// (stores ack'd at coherent point) -> relaxed agent atomicAdd; blocks 0..255
// spin, one ACQUIRE (buffer_inv) drops stale L2, then out-phase with normal
// vectorized loads. All 512 blocks co-resident (2 blk/CU x 256 CU).
// ---------------------------------------------------------------------------
__global__ __launch_bounds__(256, 2) void mempool_fused(
    const float* __restrict__ x, const float* __restrict__ ktq,
    const float* __restrict__ conv_w, const float* __restrict__ lin_w,
    float* __restrict__ S_out, uint32* __restrict__ part,
    unsigned* __restrict__ bar, float* __restrict__ out) {
  const int t = threadIdx.x;
  const int hkp = t & 63;
  const int q = t >> 6;  // f-quarter 0..3

  __shared__ float4 xl[P1_PTS * 32];      // [p][fq], 8 KB
  __shared__ float accs[P1_PTS][4][128];  // [p][q][hk], 32 KB
  __shared__ float cwsn[P1_PTS][4][32];   // [p][h][k], 8 KB
  __shared__ float sl[P1_PTS][32];        // [p][k], 2 KB

  const int bn0 = blockIdx.x * P1_PTS;

  // ---- A-phase ------------------------------------------------------------
  {
    const float4* xg = reinterpret_cast<const float4*>(x) + (size_t)bn0 * 32;
    xl[t] = xg[t];
    xl[t + 256] = xg[t + 256];
  }
  __syncthreads();

  const float4* kq =
      reinterpret_cast<const float4*>(ktq) + (size_t)(q * 8) * 128 + hkp;

  float acc0[P1_PTS], acc1[P1_PTS];
#pragma unroll
  for (int p = 0; p < P1_PTS; ++p) acc0[p] = acc1[p] = 0.f;

#pragma unroll
  for (int j = 0; j < 8; ++j) {
    const float4 kv0 = kq[j * 128];       // coalesced (lanes 0..63 contiguous)
    const float4 kv1 = kq[j * 128 + 64];  // second key row
    const int jj = q * 8 + j;
#pragma unroll
    for (int p = 0; p < P1_PTS; ++p) {
      const float4 xv = xl[p * 32 + jj];  // uniform ds_read -> broadcast
      acc0[p] += fabsf(kv0.x - xv.x) + fabsf(kv0.y - xv.y) +
                 fabsf(kv0.z - xv.z) + fabsf(kv0.w - xv.w);
      acc1[p] += fabsf(kv1.x - xv.x) + fabsf(kv1.y - xv.y) +
                 fabsf(kv1.z - xv.z) + fabsf(kv1.w - xv.w);
    }
  }

#pragma unroll
  for (int p = 0; p < P1_PTS; ++p) {
    accs[p][q][hkp] = acc0[p];
    accs[p][q][hkp + 64] = acc1[p];
  }
  __syncthreads();

  // Quarter-combine + Student-t + per-head normalize.
  const float4 cwv = *reinterpret_cast<const float4*>(conv_w);
  {
    const int hk = t & 127;
    const float cw = (hk & 64) ? ((hk & 32) ? cwv.w : cwv.z)
                               : ((hk & 32) ? cwv.y : cwv.x);
#pragma unroll
    for (int i = 0; i < 8; ++i) {
      const int p = (t >> 7) + 2 * i;
      const float d = accs[p][0][hk] + accs[p][1][hk] + accs[p][2][hk] +
                      accs[p][3][hk];
      const float tv = __builtin_amdgcn_rcpf(1.f + d * d);  // Student-t, tau=1
      float hs = tv;
#pragma unroll
      for (int m = 1; m < 32; m <<= 1) hs += __shfl_xor(hs, m);
      cwsn[p][hk >> 5][hk & 31] = cw * tv * __builtin_amdgcn_rcpf(hs);
    }
  }
  __syncthreads();

  // Conv-combine over heads + softmax over k. 16 p x 32 k = 2 passes.
#pragma unroll
  for (int pp = 0; pp < 2; ++pp) {
    const int p = pp * 8 + (t >> 5);
    const int k = t & 31;
    float sc = cwsn[p][0][k] + cwsn[p][1][k] + cwsn[p][2][k] + cwsn[p][3][k];
    float mx = sc;
#pragma unroll
    for (int m = 1; m < 32; m <<= 1) mx = fmaxf(mx, __shfl_xor(mx, m));
    const float e = __expf(sc - mx);
    float se = e;
#pragma unroll
    for (int m = 1; m < 32; m <<= 1) se += __shfl_xor(se, m);
    const float sv = e * __builtin_amdgcn_rcpf(se);
    S_out[(size_t)(bn0 + p) * 32 + k] = sv;
    sl[p][k] = sv;
  }
  __syncthreads();

  // Partial pooled (bf16 pairs in uint32), written with two coalesced
  // write-through dwordx4 stores (sc0 sc1 -> coherent point, no L2 dirty).
  {
    const int k = t & 31;
    const int fs = t >> 5;
    float4 a0 = {0, 0, 0, 0}, a1 = {0, 0, 0, 0}, a2 = {0, 0, 0, 0},
           a3 = {0, 0, 0, 0};
#pragma unroll
    for (int p = 0; p < P1_PTS; ++p) {
      const float s = sl[p][k];
      const float4 v0 = xl[p * 32 + fs * 4 + 0];
      const float4 v1 = xl[p * 32 + fs * 4 + 1];
      const float4 v2 = xl[p * 32 + fs * 4 + 2];
      const float4 v3 = xl[p * 32 + fs * 4 + 3];
      a0.x += s * v0.x; a0.y += s * v0.y; a0.z += s * v0.z; a0.w += s * v0.w;
      a1.x += s * v1.x; a1.y += s * v1.y; a1.z += s * v1.z; a1.w += s * v1.w;
      a2.x += s * v2.x; a2.y += s * v2.y; a2.z += s * v2.z; a2.w += s * v2.w;
      a3.x += s * v3.x; a3.y += s * v3.y; a3.z += s * v3.z; a3.w += s * v3.w;
    }
    uint32x4 lo, hi;
    lo.x = f2bf(a0.x) | ((uint32)f2bf(a0.y) << 16);
    lo.y = f2bf(a0.z) | ((uint32)f2bf(a0.w) << 16);
    lo.z = f2bf(a1.x) | ((uint32)f2bf(a1.y) << 16);
    lo.w = f2bf(a1.z) | ((uint32)f2bf(a1.w) << 16);
    hi.x = f2bf(a2.x) | ((uint32)f2bf(a2.y) << 16);
    hi.y = f2bf(a2.z) | ((uint32)f2bf(a2.w) << 16);
    hi.z = f2bf(a3.x) | ((uint32)f2bf(a3.y) << 16);
    hi.w = f2bf(a3.z) | ((uint32)f2bf(a3.w) << 16);
    uint32* dst0 = part + (((size_t)blockIdx.x * 32 + k) * 64 + fs * 8);
    uint32* dst1 = dst0 + 4;
    asm volatile("global_store_dwordx4 %0, %1, off sc0 sc1"
                 :
                 : "v"(dst0), "v"(lo)
                 : "memory");
    asm volatile("global_store_dwordx4 %0, %1, off sc0 sc1"
                 :
                 : "v"(dst1), "v"(hi)
                 : "memory");
  }

  // ---- fence-free device barrier -----------------------------------------
  __syncthreads();
  asm volatile("s_waitcnt vmcnt(0)" ::: "memory");  // stores ack'd @ coherent pt
  if (t == 0)
    __hip_atomic_fetch_add(bar, 1u, __ATOMIC_RELAXED,
                           __HIP_MEMORY_SCOPE_AGENT);
  if (blockIdx.x >= 256) return;  // non-out blocks free their CU slot

  if (t == 0) {
    while (__hip_atomic_load(bar, __ATOMIC_RELAXED,
                             __HIP_MEMORY_SCOPE_AGENT) < (unsigned)P1_BLOCKS)
      __builtin_amdgcn_s_sleep(2);
    // single ACQUIRE (buffer_inv): drop stale L2 lines so the normal
    // vectorized part reads below refetch from the coherent point.
    (void)__hip_atomic_load(bar, __ATOMIC_ACQUIRE, __HIP_MEMORY_SCOPE_AGENT);
  }
  __syncthreads();

  // ---- out-phase (blocks 0..255 = (b = bid>>5, k = bid&31)) --------------
  {
    const int b = blockIdx.x >> 5;
    const int k = blockIdx.x & 31;
    const int f2 = t & 63;
    const int ch = t >> 6;  // 0..3

    float* red = &accs[0][0][0];     // alias: [4][128]
    float* pooled = &cwsn[0][0][0];  // alias: [128]

    float sx = 0.f, sy = 0.f;
    const uint32* pp =
        part + ((size_t)((b * NCHUNK_B + ch * 16) * 32 + k)) * 64 + f2;
#pragma unroll
    for (int cc = 0; cc < 16; ++cc) {
      const uint32 v = pp[(size_t)cc * 32 * 64];
      sx += __uint_as_float(v << 16);
      sy += __uint_as_float(v & 0xFFFF0000u);
    }
    red[ch * 128 + f2 * 2] = sx;
    red[ch * 128 + f2 * 2 + 1] = sy;
    __syncthreads();

    if (t < 128)
      pooled[t] = red[0 * 128 + t] + red[1 * 128 + t] + red[2 * 128 + t] +
                  red[3 * 128 + t];
    __syncthreads();

    if (t < 128) {
      const float4* w4 = reinterpret_cast<const float4*>(lin_w) + t * 32;
      const float4* pl4 = reinterpret_cast<const float4*>(pooled);
      float o = 0.f;
#pragma unroll
      for (int j = 0; j < 32; ++j) {
        const float4 w = w4[j];
        const float4 p = pl4[j];
        o += w.x * p.x + w.y * p.y + w.z * p.z + w.w * p.w;
      }
      o = (o >= 0.f) ? o : 0.01f * o;
      out[(size_t)(b * 32 + k) * 128 + t] = o;
    }
  }
}

// ---------------------------------------------------------------------------
// Fallbacks (no workspace): round-1 structure (known-good).
// ---------------------------------------------------------------------------
__global__ __launch_bounds__(256) void mempool_phase1_fb(
    const float* __restrict__ x, const float* __restrict__ keys,
    const float* __restrict__ conv_w, float* __restrict__ S_out) {
  const int t = threadIdx.x;
  const int hk = t & 127;
  const int half = t >> 7;

  const float4* kq = reinterpret_cast<const float4*>(keys) + hk * 32 + half * 16;
  const float cw = conv_w[(t >> 5) & 3];

  __shared__ float lds_half[128];
  __shared__ float lds_ws[128];

  const int base = blockIdx.x * 8;
  for (int p = 0; p < 8; ++p) {
    const int bn = base + p;
    const float4* xq = reinterpret_cast<const float4*>(x) + bn * 32 + half * 16;
    float a0 = 0.f;
#pragma unroll
    for (int j = 0; j < 16; ++j) {
      const float4 kv = kq[j];
      const float4 xv = xq[j];
      a0 += fabsf(kv.x - xv.x) + fabsf(kv.y - xv.y) + fabsf(kv.z - xv.z) +
            fabsf(kv.w - xv.w);
    }
    if (t >= 128) lds_half[hk] = a0;
    __syncthreads();
    if (t < 128) {
      const float d = a0 + lds_half[hk];
      const float tv = 1.0f / (1.0f + d * d);
      float hs = tv;
#pragma unroll
      for (int m = 1; m < 32; m <<= 1) hs += __shfl_xor(hs, m);
      lds_ws[hk] = cw * tv / hs;
    }
    __syncthreads();
    if (t < 32) {
      float sc = lds_ws[t] + lds_ws[32 + t] + lds_ws[64 + t] + lds_ws[96 + t];
      float mx = sc;
#pragma unroll
      for (int m = 1; m < 32; m <<= 1) mx = fmaxf(mx, __shfl_xor(mx, m));
      const float e = __expf(sc - mx);
      float se = e;
#pragma unroll
      for (int m = 1; m < 32; m <<= 1) se += __shfl_xor(se, m);
      S_out[bn * 32 + t] = e / se;
    }
    __syncthreads();
  }
}

__global__ __launch_bounds__(256) void mempool_phase2_fb(
    const float* __restrict__ x, const float* __restrict__ S,
    const float* __restrict__ lin_w, float* __restrict__ out) {
  const int b = blockIdx.x >> 5;
  const int k = blockIdx.x & 31;
  const int t = threadIdx.x;
  const int fq = t & 31;
  const int seg = t >> 5;

  const float4* xq = reinterpret_cast<const float4*>(x) + (size_t)b * 1024 * 32;
  const float* Sb = S + (size_t)b * 1024 * 32 + k;

  float4 acc = {0.f, 0.f, 0.f, 0.f};
  const int n0 = seg * 128;
#pragma unroll 4
  for (int n = n0; n < n0 + 128; ++n) {
    const float sv = Sb[(size_t)n * 32];
    const float4 xv = xq[n * 32 + fq];
    acc.x += sv * xv.x;
    acc.y += sv * xv.y;
    acc.z += sv * xv.z;
    acc.w += sv * xv.w;
  }

  __shared__ float4 red[8][32];
  red[seg][fq] = acc;
  __syncthreads();

  __shared__ float4 pooled4[32];
  if (t < 32) {
    float4 a = red[0][t];
#pragma unroll
    for (int ss = 1; ss < 8; ++ss) {
      const float4 r = red[ss][t];
      a.x += r.x; a.y += r.y; a.z += r.z; a.w += r.w;
    }
    pooled4[t] = a;
  }
  __syncthreads();

  if (t < 128) {
    const float4* wq = reinterpret_cast<const float4*>(lin_w) + t * 32;
    float o = 0.f;
#pragma unroll
    for (int j = 0; j < 32; ++j) {
      const float4 w = wq[j];
      const float4 p = pooled4[j];
      o += w.x * p.x + w.y * p.y + w.z * p.z + w.w * p.w;
    }
    o = (o >= 0.f) ? o : 0.01f * o;
    out[(size_t)(b * 32 + k) * 128 + t] = o;
  }
}

extern "C" void kernel_launch(void* const* d_in, const int* in_sizes, int n_in,
                              void* d_out, int out_size, void* d_ws, size_t ws_size,
                              hipStream_t stream) {
  const float* x = (const float*)d_in[0];       // [8,1024,128]
  const float* keys = (const float*)d_in[1];    // [4,32,128]
  const float* conv_w = (const float*)d_in[2];  // [4]
  const float* lin_w = (const float*)d_in[3];   // [128,128]

  float* out = (float*)d_out;            // [8,32,128]
  float* S_out = (float*)d_out + 32768;  // [8,1024,32]

  const size_t ktq_bytes = 128 * 128 * sizeof(float);          // 64 KB
  const size_t part_bytes = (size_t)P1_BLOCKS * 32 * 128 * 2;  // 4 MB
  const size_t bar_bytes = 64;
  const size_t need = ktq_bytes + part_bytes + bar_bytes;

  if (ws_size >= need) {
    float* ktq = (float*)d_ws;
    uint32* part = (uint32*)((char*)d_ws + ktq_bytes);
    unsigned* bar = (unsigned*)((char*)d_ws + ktq_bytes + part_bytes);
    mempool_prep<<<16, 256, 0, stream>>>(keys, ktq, bar);
    mempool_fused<<<P1_BLOCKS, 256, 0, stream>>>(x, ktq, conv_w, lin_w, S_out,
                                                 part, bar, out);
  } else {
    mempool_phase1_fb<<<1024, 256, 0, stream>>>(x, keys, conv_w, S_out);
    mempool_phase2_fb<<<8 * 32, 256, 0, stream>>>(x, S_out, lin_w, out);
  }
}

// Round 13
// 32.172 us; speedup vs baseline: 3.3746x; 1.4760x over previous
//
#include <hip/hip_runtime.h>

// Problem constants: B=8, N=1024, F=128, H=4, K=32, TAU=1
typedef unsigned int uint32;
typedef unsigned short ushort16;
typedef unsigned int uint32x4 __attribute__((ext_vector_type(4)));

#define P1_PTS 16      // points per A-block
#define P1_BLOCKS 512  // 8192 / P1_PTS; 50KB LDS + 256thr -> 2 blk/CU, all co-resident
#define CPB 64         // chunks (blocks) per batch = 1024 / P1_PTS
#define TAILS 8        // tail blocks per batch (last 8 to finish)
#define KPT 4          // k-columns per tail block (TAILS*KPT = 32)

// round-to-nearest-even f32 -> bf16 bits
static __device__ __forceinline__ ushort16 f2bf(float f) {
  uint32 u = __float_as_uint(f);
  return (ushort16)((u + 0x7FFFu + ((u >> 16) & 1u)) >> 16);
}

// ---------------------------------------------------------------------------
// Prep: transpose keys into KTQ[fq][hk] and zero the 8 per-batch completion
// counters (64B-spaced; re-zeroed every call -> graph-replay deterministic).
// ---------------------------------------------------------------------------
__global__ __launch_bounds__(256) void mempool_prep(
    const float* __restrict__ keys, float* __restrict__ ktq,
    unsigned* __restrict__ bar) {
  if (blockIdx.x == 0 && threadIdx.x < 128)
    __hip_atomic_store(bar + threadIdx.x, 0u, __ATOMIC_RELAXED,
                       __HIP_MEMORY_SCOPE_AGENT);
  const int i = blockIdx.x * 256 + threadIdx.x;  // 0..4095
  const int fq = i >> 7;
  const int hk = i & 127;
  reinterpret_cast<float4*>(ktq)[i] =
      reinterpret_cast<const float4*>(keys)[hk * 32 + fq];
}

// ---------------------------------------------------------------------------
// Fused kernel, NO grid barrier. A-phase (r12-identical): distances ->
// Student-t -> normalize -> conv -> softmax -> S_out; bf16 partial pooled ->
// part via coalesced write-through stores (sc0 sc1 -> coherent point).
// Then: vmcnt(0) + one relaxed agent fetch_add on this BATCH's counter
// (64 blocks/batch). The returned count tells a block if it is among the
// last TAILS finishers; those 8 blocks each reduce 4 k-columns of the batch
// (64 chunks) + matvec + LeakyReLU. The old==63 block needs no wait at all;
// old in [56,62] spin ~1-2us on <=7 stragglers, then one ACQUIRE
// (buffer_inv, r12-proven) before reading part.
// ---------------------------------------------------------------------------
__global__ __launch_bounds__(256, 2) void mempool_fused(
    const float* __restrict__ x, const float* __restrict__ ktq,
    const float* __restrict__ conv_w, const float* __restrict__ lin_w,
    float* __restrict__ S_out, uint32* __restrict__ part,
    unsigned* __restrict__ bar, float* __restrict__ out) {
  const int t = threadIdx.x;
  const int hkp = t & 63;
  const int q = t >> 6;  // f-quarter 0..3

  __shared__ float4 xl[P1_PTS * 32];      // [p][fq], 8 KB
  __shared__ float accs[P1_PTS][4][128];  // [p][q][hk], 32 KB
  __shared__ float cwsn[P1_PTS][4][32];   // [p][h][k], 8 KB
  __shared__ float sl[P1_PTS][32];        // [p][k], 2 KB
  __shared__ unsigned oldv;

  const int bn0 = blockIdx.x * P1_PTS;

  // ---- A-phase (identical to r12) ----------------------------------------
  {
    const float4* xg = reinterpret_cast<const float4*>(x) + (size_t)bn0 * 32;
    xl[t] = xg[t];
    xl[t + 256] = xg[t + 256];
  }
  __syncthreads();

  const float4* kq =
      reinterpret_cast<const float4*>(ktq) + (size_t)(q * 8) * 128 + hkp;

  float acc0[P1_PTS], acc1[P1_PTS];
#pragma unroll
  for (int p = 0; p < P1_PTS; ++p) acc0[p] = acc1[p] = 0.f;

#pragma unroll
  for (int j = 0; j < 8; ++j) {
    const float4 kv0 = kq[j * 128];       // coalesced (lanes 0..63 contiguous)
    const float4 kv1 = kq[j * 128 + 64];  // second key row
    const int jj = q * 8 + j;
#pragma unroll
    for (int p = 0; p < P1_PTS; ++p) {
      const float4 xv = xl[p * 32 + jj];  // uniform ds_read -> broadcast
      acc0[p] += fabsf(kv0.x - xv.x) + fabsf(kv0.y - xv.y) +
                 fabsf(kv0.z - xv.z) + fabsf(kv0.w - xv.w);
      acc1[p] += fabsf(kv1.x - xv.x) + fabsf(kv1.y - xv.y) +
                 fabsf(kv1.z - xv.z) + fabsf(kv1.w - xv.w);
    }
  }

#pragma unroll
  for (int p = 0; p < P1_PTS; ++p) {
    accs[p][q][hkp] = acc0[p];
    accs[p][q][hkp + 64] = acc1[p];
  }
  __syncthreads();

  // Quarter-combine + Student-t + per-head normalize.
  const float4 cwv = *reinterpret_cast<const float4*>(conv_w);
  {
    const int hk = t & 127;
    const float cw = (hk & 64) ? ((hk & 32) ? cwv.w : cwv.z)
                               : ((hk & 32) ? cwv.y : cwv.x);
#pragma unroll
    for (int i = 0; i < 8; ++i) {
      const int p = (t >> 7) + 2 * i;
      const float d = accs[p][0][hk] + accs[p][1][hk] + accs[p][2][hk] +
                      accs[p][3][hk];
      const float tv = __builtin_amdgcn_rcpf(1.f + d * d);  // Student-t, tau=1
      float hs = tv;
#pragma unroll
      for (int m = 1; m < 32; m <<= 1) hs += __shfl_xor(hs, m);
      cwsn[p][hk >> 5][hk & 31] = cw * tv * __builtin_amdgcn_rcpf(hs);
    }
  }
  __syncthreads();

  // Conv-combine over heads + softmax over k. 16 p x 32 k = 2 passes.
#pragma unroll
  for (int pp = 0; pp < 2; ++pp) {
    const int p = pp * 8 + (t >> 5);
    const int k = t & 31;
    float sc = cwsn[p][0][k] + cwsn[p][1][k] + cwsn[p][2][k] + cwsn[p][3][k];
    float mx = sc;
#pragma unroll
    for (int m = 1; m < 32; m <<= 1) mx = fmaxf(mx, __shfl_xor(mx, m));
    const float e = __expf(sc - mx);
    float se = e;
#pragma unroll
    for (int m = 1; m < 32; m <<= 1) se += __shfl_xor(se, m);
    const float sv = e * __builtin_amdgcn_rcpf(se);
    S_out[(size_t)(bn0 + p) * 32 + k] = sv;
    sl[p][k] = sv;
  }
  __syncthreads();

  // Partial pooled (bf16 pairs in uint32), coalesced write-through stores.
  {
    const int k = t & 31;
    const int fs = t >> 5;
    float4 a0 = {0, 0, 0, 0}, a1 = {0, 0, 0, 0}, a2 = {0, 0, 0, 0},
           a3 = {0, 0, 0, 0};
#pragma unroll
    for (int p = 0; p < P1_PTS; ++p) {
      const float s = sl[p][k];
      const float4 v0 = xl[p * 32 + fs * 4 + 0];
      const float4 v1 = xl[p * 32 + fs * 4 + 1];
      const float4 v2 = xl[p * 32 + fs * 4 + 2];
      const float4 v3 = xl[p * 32 + fs * 4 + 3];
      a0.x += s * v0.x; a0.y += s * v0.y; a0.z += s * v0.z; a0.w += s * v0.w;
      a1.x += s * v1.x; a1.y += s * v1.y; a1.z += s * v1.z; a1.w += s * v1.w;
      a2.x += s * v2.x; a2.y += s * v2.y; a2.z += s * v2.z; a2.w += s * v2.w;
      a3.x += s * v3.x; a3.y += s * v3.y; a3.z += s * v3.z; a3.w += s * v3.w;
    }
    uint32x4 lo, hi;
    lo.x = f2bf(a0.x) | ((uint32)f2bf(a0.y) << 16);
    lo.y = f2bf(a0.z) | ((uint32)f2bf(a0.w) << 16);
    lo.z = f2bf(a1.x) | ((uint32)f2bf(a1.y) << 16);
    lo.w = f2bf(a1.z) | ((uint32)f2bf(a1.w) << 16);
    hi.x = f2bf(a2.x) | ((uint32)f2bf(a2.y) << 16);
    hi.y = f2bf(a2.z) | ((uint32)f2bf(a2.w) << 16);
    hi.z = f2bf(a3.x) | ((uint32)f2bf(a3.y) << 16);
    hi.w = f2bf(a3.z) | ((uint32)f2bf(a3.w) << 16);
    uint32* dst0 = part + (((size_t)blockIdx.x * 32 + k) * 64 + fs * 8);
    uint32* dst1 = dst0 + 4;
    asm volatile("global_store_dwordx4 %0, %1, off sc0 sc1"
                 :
                 : "v"(dst0), "v"(lo)
                 : "memory");
    asm volatile("global_store_dwordx4 %0, %1, off sc0 sc1"
                 :
                 : "v"(dst1), "v"(hi)
                 : "memory");
  }

  // ---- per-batch completion count (no grid barrier) ----------------------
  __syncthreads();
  asm volatile("s_waitcnt vmcnt(0)" ::: "memory");  // part ack'd @ coherent pt
  const int b = blockIdx.x >> 6;  // batch of this block (64 blocks/batch)
  unsigned* ctr = bar + b * 16;   // 64B-spaced counters
  if (t == 0)
    oldv = __hip_atomic_fetch_add(ctr, 1u, __ATOMIC_RELAXED,
                                  __HIP_MEMORY_SCOPE_AGENT);
  __syncthreads();
  const unsigned old = oldv;
  if (old < (unsigned)(CPB - TAILS)) return;  // not a tail block
  const int tidx = (int)old - (CPB - TAILS);  // 0..7

  if (t == 0) {
    // old==63 exits immediately (own add observed 64); others wait briefly.
    while (__hip_atomic_load(ctr, __ATOMIC_RELAXED,
                             __HIP_MEMORY_SCOPE_AGENT) < (unsigned)CPB)
      __builtin_amdgcn_s_sleep(2);
    // single ACQUIRE (buffer_inv): drop stale L1/L2 lines before part reads.
    (void)__hip_atomic_load(ctr, __ATOMIC_ACQUIRE, __HIP_MEMORY_SCOPE_AGENT);
  }
  __syncthreads();

  // ---- tail: reduce 64 chunks for k in [tidx*4, tidx*4+4) ----------------
  {
    const int k0 = tidx * KPT;
    const int kk = t >> 6;  // 0..3 (one k per wave)
    const int f2 = t & 63;  // feature pair
    float* pooled = &cwsn[0][0][0];  // alias [4][128]

    float sx = 0.f, sy = 0.f;
    const uint32* pp =
        part + (((size_t)(b * CPB) * 32 + (k0 + kk)) * 64) + f2;
#pragma unroll 8
    for (int c = 0; c < CPB; ++c) {
      const uint32 v = pp[(size_t)c * 32 * 64];  // 256B/wave coalesced
      sx += __uint_as_float(v << 16);
      sy += __uint_as_float(v & 0xFFFF0000u);
    }
    pooled[kk * 128 + f2 * 2] = sx;
    pooled[kk * 128 + f2 * 2 + 1] = sy;
    __syncthreads();

    if (t < 128) {  // fo = t; one lin_w row feeds 4 k outputs
      const float4* w4 = reinterpret_cast<const float4*>(lin_w) + t * 32;
      const float4* pl = reinterpret_cast<const float4*>(pooled);
      float o0 = 0.f, o1 = 0.f, o2 = 0.f, o3 = 0.f;
#pragma unroll
      for (int j = 0; j < 32; ++j) {
        const float4 w = w4[j];
        const float4 p0 = pl[j];
        const float4 p1 = pl[32 + j];
        const float4 p2 = pl[64 + j];
        const float4 p3 = pl[96 + j];
        o0 += w.x * p0.x + w.y * p0.y + w.z * p0.z + w.w * p0.w;
        o1 += w.x * p1.x + w.y * p1.y + w.z * p1.z + w.w * p1.w;
        o2 += w.x * p2.x + w.y * p2.y + w.z * p2.z + w.w * p2.w;
        o3 += w.x * p3.x + w.y * p3.y + w.z * p3.z + w.w * p3.w;
      }
      o0 = (o0 >= 0.f) ? o0 : 0.01f * o0;
      o1 = (o1 >= 0.f) ? o1 : 0.01f * o1;
      o2 = (o2 >= 0.f) ? o2 : 0.01f * o2;
      o3 = (o3 >= 0.f) ? o3 : 0.01f * o3;
      float* ob = out + ((size_t)(b * 32 + k0) * 128) + t;
      ob[0] = o0;
      ob[128] = o1;
      ob[256] = o2;
      ob[384] = o3;
    }
  }
}

// ---------------------------------------------------------------------------
// Fallbacks (no workspace): round-1 structure (known-good).
// ---------------------------------------------------------------------------
__global__ __launch_bounds__(256) void mempool_phase1_fb(
    const float* __restrict__ x, const float* __restrict__ keys,
    const float* __restrict__ conv_w, float* __restrict__ S_out) {
  const int t = threadIdx.x;
  const int hk = t & 127;
  const int half = t >> 7;

  const float4* kq = reinterpret_cast<const float4*>(keys) + hk * 32 + half * 16;
  const float cw = conv_w[(t >> 5) & 3];

  __shared__ float lds_half[128];
  __shared__ float lds_ws[128];

  const int base = blockIdx.x * 8;
  for (int p = 0; p < 8; ++p) {
    const int bn = base + p;
    const float4* xq = reinterpret_cast<const float4*>(x) + bn * 32 + half * 16;
    float a0 = 0.f;
#pragma unroll
    for (int j = 0; j < 16; ++j) {
      const float4 kv = kq[j];
      const float4 xv = xq[j];
      a0 += fabsf(kv.x - xv.x) + fabsf(kv.y - xv.y) + fabsf(kv.z - xv.z) +
            fabsf(kv.w - xv.w);
    }
    if (t >= 128) lds_half[hk] = a0;
    __syncthreads();
    if (t < 128) {
      const float d = a0 + lds_half[hk];
      const float tv = 1.0f / (1.0f + d * d);
      float hs = tv;
#pragma unroll
      for (int m = 1; m < 32; m <<= 1) hs += __shfl_xor(hs, m);
      lds_ws[hk] = cw * tv / hs;
    }
    __syncthreads();
    if (t < 32) {
      float sc = lds_ws[t] + lds_ws[32 + t] + lds_ws[64 + t] + lds_ws[96 + t];
      float mx = sc;
#pragma unroll
      for (int m = 1; m < 32; m <<= 1) mx = fmaxf(mx, __shfl_xor(mx, m));
      const float e = __expf(sc - mx);
      float se = e;
#pragma unroll
      for (int m = 1; m < 32; m <<= 1) se += __shfl_xor(se, m);
      S_out[bn * 32 + t] = e / se;
    }
    __syncthreads();
  }
}

__global__ __launch_bounds__(256) void mempool_phase2_fb(
    const float* __restrict__ x, const float* __restrict__ S,
    const float* __restrict__ lin_w, float* __restrict__ out) {
  const int b = blockIdx.x >> 5;
  const int k = blockIdx.x & 31;
  const int t = threadIdx.x;
  const int fq = t & 31;
  const int seg = t >> 5;

  const float4* xq = reinterpret_cast<const float4*>(x) + (size_t)b * 1024 * 32;
  const float* Sb = S + (size_t)b * 1024 * 32 + k;

  float4 acc = {0.f, 0.f, 0.f, 0.f};
  const int n0 = seg * 128;
#pragma unroll 4
  for (int n = n0; n < n0 + 128; ++n) {
    const float sv = Sb[(size_t)n * 32];
    const float4 xv = xq[n * 32 + fq];
    acc.x += sv * xv.x;
    acc.y += sv * xv.y;
    acc.z += sv * xv.z;
    acc.w += sv * xv.w;
  }

  __shared__ float4 red[8][32];
  red[seg][fq] = acc;
  __syncthreads();

  __shared__ float4 pooled4[32];
  if (t < 32) {
    float4 a = red[0][t];
#pragma unroll
    for (int ss = 1; ss < 8; ++ss) {
      const float4 r = red[ss][t];
      a.x += r.x; a.y += r.y; a.z += r.z; a.w += r.w;
    }
    pooled4[t] = a;
  }
  __syncthreads();

  if (t < 128) {
    const float4* wq = reinterpret_cast<const float4*>(lin_w) + t * 32;
    float o = 0.f;
#pragma unroll
    for (int j = 0; j < 32; ++j) {
      const float4 w = wq[j];
      const float4 p = pooled4[j];
      o += w.x * p.x + w.y * p.y + w.z * p.z + w.w * p.w;
    }
    o = (o >= 0.f) ? o : 0.01f * o;
    out[(size_t)(b * 32 + k) * 128 + t] = o;
  }
}

extern "C" void kernel_launch(void* const* d_in, const int* in_sizes, int n_in,
                              void* d_out, int out_size, void* d_ws, size_t ws_size,
                              hipStream_t stream) {
  const float* x = (const float*)d_in[0];       // [8,1024,128]
  const float* keys = (const float*)d_in[1];    // [4,32,128]
  const float* conv_w = (const float*)d_in[2];  // [4]
  const float* lin_w = (const float*)d_in[3];   // [128,128]

  float* out = (float*)d_out;            // [8,32,128]
  float* S_out = (float*)d_out + 32768;  // [8,1024,32]

  const size_t ktq_bytes = 128 * 128 * sizeof(float);          // 64 KB
  const size_t part_bytes = (size_t)P1_BLOCKS * 32 * 128 * 2;  // 4 MB
  const size_t bar_bytes = 128 * sizeof(unsigned);             // 512 B
  const size_t need = ktq_bytes + part_bytes + bar_bytes;

  if (ws_size >= need) {
    float* ktq = (float*)d_ws;
    uint32* part = (uint32*)((char*)d_ws + ktq_bytes);
    unsigned* bar = (unsigned*)((char*)d_ws + ktq_bytes + part_bytes);
    mempool_prep<<<16, 256, 0, stream>>>(keys, ktq, bar);
    mempool_fused<<<P1_BLOCKS, 256, 0, stream>>>(x, ktq, conv_w, lin_w, S_out,
                                                 part, bar, out);
  } else {
    mempool_phase1_fb<<<1024, 256, 0, stream>>>(x, keys, conv_w, S_out);
    mempool_phase2_fb<<<8 * 32, 256, 0, stream>>>(x, S_out, lin_w, out);
  }
}

// Round 14
// 22.496 us; speedup vs baseline: 4.8260x; 1.4301x over previous
//
#include <hip/hip_runtime.h>

// Problem constants: B=8, N=1024, F=128, H=4, K=32, TAU=1
typedef unsigned int uint32;
typedef unsigned short ushort16;

#define P1_PTS 16      // points per A-block
#define P1_BLOCKS 512  // 8192 / P1_PTS
#define NCHUNK_B 64    // chunks per batch = 1024 / P1_PTS

// round-to-nearest-even f32 -> bf16 bits
static __device__ __forceinline__ ushort16 f2bf(float f) {
  uint32 u = __float_as_uint(f);
  return (ushort16)((u + 0x7FFFu + ((u >> 16) & 1u)) >> 16);
}

// ---------------------------------------------------------------------------
// A: per block of 16 points: L1 distances (keys read DIRECTLY from the
// original [hk][f] layout — per-thread j-loads walk a 512B row in 16B steps,
// 16KB/wave working set -> L1-cached, no transpose kernel needed) ->
// Student-t -> per-head normalize -> conv-combine -> softmax -> S_out,
// then bf16 partial pooled -> part (normal cached stores; the kernel
// boundary makes them visible to the out kernel). r8-proven math.
// ---------------------------------------------------------------------------
__global__ __launch_bounds__(256, 2) void mempool_A(
    const float* __restrict__ x, const float* __restrict__ keys,
    const float* __restrict__ conv_w, float* __restrict__ S_out,
    uint32* __restrict__ part) {
  const int t = threadIdx.x;
  const int hkp = t & 63;
  const int q = t >> 6;  // f-quarter 0..3

  __shared__ float4 xl[P1_PTS * 32];      // [p][fq], 8 KB
  __shared__ float accs[P1_PTS][4][128];  // [p][q][hk], 32 KB
  __shared__ float cwsn[P1_PTS][4][32];   // [p][h][k], 8 KB
  __shared__ float sl[P1_PTS][32];        // [p][k], 2 KB

  const int bn0 = blockIdx.x * P1_PTS;

  // Stage x: 512 float4 = 2 per thread, fully coalesced.
  {
    const float4* xg = reinterpret_cast<const float4*>(x) + (size_t)bn0 * 32;
    xl[t] = xg[t];
    xl[t + 256] = xg[t + 256];
  }
  __syncthreads();

  // Key rows hkp and hkp+64, f-quarter q, original layout (L1-resident).
  const float4* kr0 =
      reinterpret_cast<const float4*>(keys + (size_t)hkp * 128 + q * 32);
  const float4* kr1 =
      reinterpret_cast<const float4*>(keys + (size_t)(hkp + 64) * 128 + q * 32);

  float acc0[P1_PTS], acc1[P1_PTS];
#pragma unroll
  for (int p = 0; p < P1_PTS; ++p) acc0[p] = acc1[p] = 0.f;

#pragma unroll
  for (int j = 0; j < 8; ++j) {
    const float4 kv0 = kr0[j];
    const float4 kv1 = kr1[j];
    const int jj = q * 8 + j;
#pragma unroll
    for (int p = 0; p < P1_PTS; ++p) {
      const float4 xv = xl[p * 32 + jj];  // uniform ds_read -> broadcast
      acc0[p] += fabsf(kv0.x - xv.x) + fabsf(kv0.y - xv.y) +
                 fabsf(kv0.z - xv.z) + fabsf(kv0.w - xv.w);
      acc1[p] += fabsf(kv1.x - xv.x) + fabsf(kv1.y - xv.y) +
                 fabsf(kv1.z - xv.z) + fabsf(kv1.w - xv.w);
    }
  }

#pragma unroll
  for (int p = 0; p < P1_PTS; ++p) {
    accs[p][q][hkp] = acc0[p];
    accs[p][q][hkp + 64] = acc1[p];
  }
  __syncthreads();

  // Quarter-combine + Student-t + per-head normalize.
  // 2048 (p,hk) cells / 256 threads = 8 each; 32-lane groups share (p,h).
  const float4 cwv = *reinterpret_cast<const float4*>(conv_w);
  {
    const int hk = t & 127;
    const float cw = (hk & 64) ? ((hk & 32) ? cwv.w : cwv.z)
                               : ((hk & 32) ? cwv.y : cwv.x);
#pragma unroll
    for (int i = 0; i < 8; ++i) {
      const int p = (t >> 7) + 2 * i;
      const float d = accs[p][0][hk] + accs[p][1][hk] + accs[p][2][hk] +
                      accs[p][3][hk];
      const float tv = __builtin_amdgcn_rcpf(1.f + d * d);  // Student-t, tau=1
      float hs = tv;
#pragma unroll
      for (int m = 1; m < 32; m <<= 1) hs += __shfl_xor(hs, m);
      cwsn[p][hk >> 5][hk & 31] = cw * tv * __builtin_amdgcn_rcpf(hs);
    }
  }
  __syncthreads();

  // Conv-combine over heads + softmax over k. 16 p x 32 k = 2 passes.
#pragma unroll
  for (int pp = 0; pp < 2; ++pp) {
    const int p = pp * 8 + (t >> 5);
    const int k = t & 31;
    float sc = cwsn[p][0][k] + cwsn[p][1][k] + cwsn[p][2][k] + cwsn[p][3][k];
    float mx = sc;
#pragma unroll
    for (int m = 1; m < 32; m <<= 1) mx = fmaxf(mx, __shfl_xor(mx, m));
    const float e = __expf(sc - mx);
    float se = e;
#pragma unroll
    for (int m = 1; m < 32; m <<= 1) se += __shfl_xor(se, m);
    const float sv = e * __builtin_amdgcn_rcpf(se);
    S_out[(size_t)(bn0 + p) * 32 + k] = sv;
    sl[p][k] = sv;
  }
  __syncthreads();

  // Partial pooled (bf16 pairs in uint32), normal cached vector stores.
  {
    const int k = t & 31;
    const int fs = t >> 5;
    float4 a0 = {0, 0, 0, 0}, a1 = {0, 0, 0, 0}, a2 = {0, 0, 0, 0},
           a3 = {0, 0, 0, 0};
#pragma unroll
    for (int p = 0; p < P1_PTS; ++p) {
      const float s = sl[p][k];
      const float4 v0 = xl[p * 32 + fs * 4 + 0];
      const float4 v1 = xl[p * 32 + fs * 4 + 1];
      const float4 v2 = xl[p * 32 + fs * 4 + 2];
      const float4 v3 = xl[p * 32 + fs * 4 + 3];
      a0.x += s * v0.x; a0.y += s * v0.y; a0.z += s * v0.z; a0.w += s * v0.w;
      a1.x += s * v1.x; a1.y += s * v1.y; a1.z += s * v1.z; a1.w += s * v1.w;
      a2.x += s * v2.x; a2.y += s * v2.y; a2.z += s * v2.z; a2.w += s * v2.w;
      a3.x += s * v3.x; a3.y += s * v3.y; a3.z += s * v3.z; a3.w += s * v3.w;
    }
    uint32 w0 = f2bf(a0.x) | ((uint32)f2bf(a0.y) << 16);
    uint32 w1 = f2bf(a0.z) | ((uint32)f2bf(a0.w) << 16);
    uint32 w2 = f2bf(a1.x) | ((uint32)f2bf(a1.y) << 16);
    uint32 w3 = f2bf(a1.z) | ((uint32)f2bf(a1.w) << 16);
    uint32 w4 = f2bf(a2.x) | ((uint32)f2bf(a2.y) << 16);
    uint32 w5 = f2bf(a2.z) | ((uint32)f2bf(a2.w) << 16);
    uint32 w6 = f2bf(a3.x) | ((uint32)f2bf(a3.y) << 16);
    uint32 w7 = f2bf(a3.z) | ((uint32)f2bf(a3.w) << 16);
    uint4* dst = reinterpret_cast<uint4*>(
        part + (((size_t)blockIdx.x * 32 + k) * 64 + fs * 8));
    dst[0] = make_uint4(w0, w1, w2, w3);
    dst[1] = make_uint4(w4, w5, w6, w7);
  }
}

// ---------------------------------------------------------------------------
// Out: block = (b,k), 256 threads (r8-proven).
// pooled[f] = sum_{c=0..64} part[b*64+c][k][f] (bf16->f32), then
// out[b][k][fo] = leakyrelu(pooled . lin_w[fo]).
// ---------------------------------------------------------------------------
__global__ __launch_bounds__(256) void mempool_out(
    const uint32* __restrict__ part, const float* __restrict__ lin_w,
    float* __restrict__ out) {
  const int b = blockIdx.x >> 5;
  const int k = blockIdx.x & 31;
  const int t = threadIdx.x;
  const int f2 = t & 63;
  const int ch = t >> 6;  // 0..3

  __shared__ float red[4][128];
  __shared__ float pooled[128];

  float sx = 0.f, sy = 0.f;
  const uint32* pp =
      part + ((size_t)((b * NCHUNK_B + ch * 16) * 32 + k)) * 64 + f2;
#pragma unroll
  for (int cc = 0; cc < 16; ++cc) {
    const uint32 v = pp[(size_t)cc * 32 * 64];
    sx += __uint_as_float(v << 16);
    sy += __uint_as_float(v & 0xFFFF0000u);
  }
  red[ch][f2 * 2] = sx;
  red[ch][f2 * 2 + 1] = sy;
  __syncthreads();

  if (t < 128) pooled[t] = red[0][t] + red[1][t] + red[2][t] + red[3][t];
  __syncthreads();

  if (t < 128) {
    const float4* w4 = reinterpret_cast<const float4*>(lin_w) + t * 32;
    const float4* pl4 = reinterpret_cast<const float4*>(pooled);
    float o = 0.f;
#pragma unroll
    for (int j = 0; j < 32; ++j) {
      const float4 w = w4[j];
      const float4 p = pl4[j];
      o += w.x * p.x + w.y * p.y + w.z * p.z + w.w * p.w;
    }
    o = (o >= 0.f) ? o : 0.01f * o;
    out[(size_t)(b * 32 + k) * 128 + t] = o;
  }
}

// ---------------------------------------------------------------------------
// Fallbacks (no workspace): round-1 structure (known-good).
// ---------------------------------------------------------------------------
__global__ __launch_bounds__(256) void mempool_phase1_fb(
    const float* __restrict__ x, const float* __restrict__ keys,
    const float* __restrict__ conv_w, float* __restrict__ S_out) {
  const int t = threadIdx.x;
  const int hk = t & 127;
  const int half = t >> 7;

  const float4* kq = reinterpret_cast<const float4*>(keys) + hk * 32 + half * 16;
  const float cw = conv_w[(t >> 5) & 3];

  __shared__ float lds_half[128];
  __shared__ float lds_ws[128];

  const int base = blockIdx.x * 8;
  for (int p = 0; p < 8; ++p) {
    const int bn = base + p;
    const float4* xq = reinterpret_cast<const float4*>(x) + bn * 32 + half * 16;
    float a0 = 0.f;
#pragma unroll
    for (int j = 0; j < 16; ++j) {
      const float4 kv = kq[j];
      const float4 xv = xq[j];
      a0 += fabsf(kv.x - xv.x) + fabsf(kv.y - xv.y) + fabsf(kv.z - xv.z) +
            fabsf(kv.w - xv.w);
    }
    if (t >= 128) lds_half[hk] = a0;
    __syncthreads();
    if (t < 128) {
      const float d = a0 + lds_half[hk];
      const float tv = 1.0f / (1.0f + d * d);
      float hs = tv;
#pragma unroll
      for (int m = 1; m < 32; m <<= 1) hs += __shfl_xor(hs, m);
      lds_ws[hk] = cw * tv / hs;
    }
    __syncthreads();
    if (t < 32) {
      float sc = lds_ws[t] + lds_ws[32 + t] + lds_ws[64 + t] + lds_ws[96 + t];
      float mx = sc;
#pragma unroll
      for (int m = 1; m < 32; m <<= 1) mx = fmaxf(mx, __shfl_xor(mx, m));
      const float e = __expf(sc - mx);
      float se = e;
#pragma unroll
      for (int m = 1; m < 32; m <<= 1) se += __shfl_xor(se, m);
      S_out[bn * 32 + t] = e / se;
    }
    __syncthreads();
  }
}

__global__ __launch_bounds__(256) void mempool_phase2_fb(
    const float* __restrict__ x, const float* __restrict__ S,
    const float* __restrict__ lin_w, float* __restrict__ out) {
  const int b = blockIdx.x >> 5;
  const int k = blockIdx.x & 31;
  const int t = threadIdx.x;
  const int fq = t & 31;
  const int seg = t >> 5;

  const float4* xq = reinterpret_cast<const float4*>(x) + (size_t)b * 1024 * 32;
  const float* Sb = S + (size_t)b * 1024 * 32 + k;

  float4 acc = {0.f, 0.f, 0.f, 0.f};
  const int n0 = seg * 128;
#pragma unroll 4
  for (int n = n0; n < n0 + 128; ++n) {
    const float sv = Sb[(size_t)n * 32];
    const float4 xv = xq[n * 32 + fq];
    acc.x += sv * xv.x;
    acc.y += sv * xv.y;
    acc.z += sv * xv.z;
    acc.w += sv * xv.w;
  }

  __shared__ float4 red[8][32];
  red[seg][fq] = acc;
  __syncthreads();

  __shared__ float4 pooled4[32];
  if (t < 32) {
    float4 a = red[0][t];
#pragma unroll
    for (int ss = 1; ss < 8; ++ss) {
      const float4 r = red[ss][t];
      a.x += r.x; a.y += r.y; a.z += r.z; a.w += r.w;
    }
    pooled4[t] = a;
  }
  __syncthreads();

  if (t < 128) {
    const float4* wq = reinterpret_cast<const float4*>(lin_w) + t * 32;
    float o = 0.f;
#pragma unroll
    for (int j = 0; j < 32; ++j) {
      const float4 w = wq[j];
      const float4 p = pooled4[j];
      o += w.x * p.x + w.y * p.y + w.z * p.z + w.w * p.w;
    }
    o = (o >= 0.f) ? o : 0.01f * o;
    out[(size_t)(b * 32 + k) * 128 + t] = o;
  }
}

extern "C" void kernel_launch(void* const* d_in, const int* in_sizes, int n_in,
                              void* d_out, int out_size, void* d_ws, size_t ws_size,
                              hipStream_t stream) {
  const float* x = (const float*)d_in[0];       // [8,1024,128]
  const float* keys = (const float*)d_in[1];    // [4,32,128]
  const float* conv_w = (const float*)d_in[2];  // [4]
  const float* lin_w = (const float*)d_in[3];   // [128,128]

  float* out = (float*)d_out;            // [8,32,128]
  float* S_out = (float*)d_out + 32768;  // [8,1024,32]

  const size_t part_bytes = (size_t)P1_BLOCKS * 32 * 128 * 2;  // 4 MB bf16

  if (ws_size >= part_bytes) {
    uint32* part = (uint32*)d_ws;
    mempool_A<<<P1_BLOCKS, 256, 0, stream>>>(x, keys, conv_w, S_out, part);
    mempool_out<<<8 * 32, 256, 0, stream>>>(part, lin_w, out);
  } else {
    mempool_phase1_fb<<<1024, 256, 0, stream>>>(x, keys, conv_w, S_out);
    mempool_phase2_fb<<<8 * 32, 256, 0, stream>>>(x, S_out, lin_w, out);
  }
}